// Round 2
// baseline (1496.556 us; speedup 1.0000x reference)
//
#include <hip/hip_runtime.h>
#include <math.h>

#define NN 50000
#define EE 800000

typedef __attribute__((ext_vector_type(8))) short bf16x8;
typedef __attribute__((ext_vector_type(4))) float f32x4;

__device__ __forceinline__ unsigned short f2bf(float f) {
  union { float f; unsigned u; } z; z.f = f;
  return (unsigned short)((z.u + 0x7fffu + ((z.u >> 16) & 1u)) >> 16);
}
__device__ __forceinline__ float bf2f(unsigned int h16) {
  union { unsigned u; float f; } z; z.u = h16 << 16; return z.f;
}
__device__ __forceinline__ float sigm(float v) { return 1.0f / (1.0f + __expf(-v)); }

__device__ __forceinline__ bf16x8 pack8(float a0, float a1, float a2, float a3,
                                        float a4, float a5, float a6, float a7) {
  bf16x8 r;
  r[0] = (short)f2bf(a0); r[1] = (short)f2bf(a1);
  r[2] = (short)f2bf(a2); r[3] = (short)f2bf(a3);
  r[4] = (short)f2bf(a4); r[5] = (short)f2bf(a5);
  r[6] = (short)f2bf(a6); r[7] = (short)f2bf(a7);
  return r;
}

// ============ K0: pack all weights into bf16 MFMA A-fragments ============
// Frag layout (16x16x32, "A"=W[outcol][k]): lane l supplies W[ct*16+(l&15)][ks*32+(l>>4)*8+j]
// frag f occupies frags[f*512 .. f*512+511], lane slot = 16B at lane*8 elems.
// regions: [0,8) W1-edge (K=32, k<20 real); [8,40) W2; [40,104) W1-node; [104,200) Wih; [200,296) Whh
__global__ __launch_bounds__(64) void k0_prep(const float* __restrict__ W1,
                                              const float* __restrict__ W2,
                                              const float* __restrict__ Wih,
                                              const float* __restrict__ Whh,
                                              unsigned short* __restrict__ frags) {
  const int f = blockIdx.x, l = threadIdx.x;
  const int c16 = l & 15, kg = l >> 4;
  float v[8];
  if (f < 8) {
    const int c = f * 16 + c16;
#pragma unroll
    for (int j = 0; j < 8; ++j) {
      const int k = kg * 8 + j;
      v[j] = (k < 20) ? W1[(256 + k) * 128 + c] : 0.0f;
    }
  } else if (f < 40) {
    const int lf = f - 8, ct = lf >> 2, ks = lf & 3, c = ct * 16 + c16;
#pragma unroll
    for (int j = 0; j < 8; ++j) { const int k = ks * 32 + kg * 8 + j; v[j] = W2[k * 128 + c]; }
  } else if (f < 104) {
    const int lf = f - 40, ct = lf >> 2, ks = lf & 3, c = ct * 16 + c16;
#pragma unroll
    for (int j = 0; j < 8; ++j) {
      const int k = ks * 32 + kg * 8 + j;
      v[j] = (c < 128) ? W1[k * 128 + c] : W1[(128 + k) * 128 + (c - 128)];
    }
  } else if (f < 200) {
    const int lf = f - 104, ct = lf >> 2, ks = lf & 3, c = ct * 16 + c16;
#pragma unroll
    for (int j = 0; j < 8; ++j) { const int k = ks * 32 + kg * 8 + j; v[j] = Wih[c * 128 + k]; }
  } else {
    const int lf = f - 200, ct = lf >> 2, ks = lf & 3, c = ct * 16 + c16;
#pragma unroll
    for (int j = 0; j < 8; ++j) { const int k = ks * 32 + kg * 8 + j; v[j] = Whh[c * 128 + k]; }
  }
  *(bf16x8*)(frags + (size_t)f * 512 + l * 8) =
      pack8(v[0], v[1], v[2], v[3], v[4], v[5], v[6], v[7]);
}

// ============ K1: P[n][0:256] = x @ [W1_dst | W1_src]  (bf16 out) ============
__global__ __launch_bounds__(256) void k1_node_pre(const float* __restrict__ x,
                                                   const unsigned short* __restrict__ W1nf,
                                                   unsigned short* __restrict__ P) {
  const int t = threadIdx.x, lane = t & 63, w = t >> 6;
  const int kg = lane >> 4, li = lane & 15;
  const int node = blockIdx.x * 16 + li;   // 3125*16 = 50000 exact
  const f32x4 zf = {0.0f, 0.0f, 0.0f, 0.0f};
  f32x4 acc[4] = {zf, zf, zf, zf};
#pragma unroll
  for (int ks = 0; ks < 4; ++ks) {
    const float* xp = x + (size_t)node * 128 + ks * 32 + kg * 8;
    const float4 u = *(const float4*)xp, v = *(const float4*)(xp + 4);
    const bf16x8 xb = pack8(u.x, u.y, u.z, u.w, v.x, v.y, v.z, v.w);
#pragma unroll
    for (int i = 0; i < 4; ++i) {
      const int ct = w * 4 + i;
      const bf16x8 af = *(const bf16x8*)(W1nf + (size_t)(ct * 4 + ks) * 512 + lane * 8);
      acc[i] = __builtin_amdgcn_mfma_f32_16x16x32_bf16(af, xb, acc[i], 0, 0, 0);
    }
  }
#pragma unroll
  for (int i = 0; i < 4; ++i) {
    const int c0 = (w * 4 + i) * 16 + kg * 4;
    const unsigned lo = f2bf(acc[i][0]) | ((unsigned)f2bf(acc[i][1]) << 16);
    const unsigned hi = f2bf(acc[i][2]) | ((unsigned)f2bf(acc[i][3]) << 16);
    *(uint2*)(P + (size_t)node * 256 + c0) = make_uint2(lo, hi);
  }
}

// ============ K2: fused edge kernel (MFMA) ============
__global__ __launch_bounds__(256) void k2_edge(const unsigned short* __restrict__ P,
                                               const float* __restrict__ edge_attr,
                                               const float* __restrict__ pos,
                                               const int* __restrict__ ei,
                                               const unsigned short* __restrict__ W1ef,
                                               const unsigned short* __restrict__ W2f,
                                               const float* __restrict__ b1,
                                               const float* __restrict__ ln1g,
                                               const float* __restrict__ ln1b,
                                               float* __restrict__ sums,
                                               float* __restrict__ cnt) {
  __shared__ unsigned short htile[64][136];   // stride 272B = 17*16 -> bank-balanced b128
  __shared__ float4 relv[64];
  __shared__ int dsts[64], srcs[64];
  __shared__ float b1s[128], g1s[128], bb1s[128];

  const int t = threadIdx.x, lane = t & 63, w = t >> 6;
  const int kg = lane >> 4, li = lane & 15;
  const int e0 = blockIdx.x * 64;   // 12500*64 = 800000 exact

  if (t < 128) { b1s[t] = b1[t]; g1s[t] = ln1g[t]; bb1s[t] = ln1b[t]; }
  if (t < 64) {
    const int e = e0 + t;
    const int s = ei[e], d = ei[EE + e];
    srcs[t] = s; dsts[t] = d;
    const float rx = (pos[3 * s + 0] - pos[3 * d + 0]) * 0.2f;
    const float ry = (pos[3 * s + 1] - pos[3 * d + 1]) * 0.2f;
    const float rz = (pos[3 * s + 2] - pos[3 * d + 2]) * 0.2f;
    relv[t] = make_float4(rx, ry, rz, rx * rx + ry * ry + rz * rz);
  }
  __syncthreads();

  // issue P gathers early (A2 mapping: 4 threads per edge, 32 cols each)
  const int e2 = t >> 2, cg = t & 3;
  const int dn = dsts[e2], sn = srcs[e2];
  const uint4* pdp = (const uint4*)(P + (size_t)dn * 256 + cg * 32);
  const uint4* psp = (const uint4*)(P + (size_t)sn * 256 + 128 + cg * 32);
  uint4 PV[4] = {pdp[0], pdp[1], pdp[2], pdp[3]};
  uint4 SV[4] = {psp[0], psp[1], psp[2], psp[3]};

  // ---- A1: pre_edgepart = (ea|geom) @ W1[256:276]  via MFMA (transposed D) ----
  const int el = w * 16 + li;
  bf16x8 bfrag;
  if (kg == 0 || kg == 1) {
    const float* ep = edge_attr + (size_t)(e0 + el) * 16 + kg * 8;
    const float4 u = *(const float4*)ep, v = *(const float4*)(ep + 4);
    bfrag = pack8(u.x, u.y, u.z, u.w, v.x, v.y, v.z, v.w);
  } else if (kg == 2) {
    const float4 rv = relv[el];
    bfrag = pack8(rv.x, rv.y, rv.z, rv.w, 0.f, 0.f, 0.f, 0.f);
  } else {
    bfrag = pack8(0.f, 0.f, 0.f, 0.f, 0.f, 0.f, 0.f, 0.f);
  }
  const f32x4 zf = {0.0f, 0.0f, 0.0f, 0.0f};
#pragma unroll
  for (int cf = 0; cf < 8; ++cf) {
    const bf16x8 af = *(const bf16x8*)(W1ef + (size_t)cf * 512 + lane * 8);
    const f32x4 d = __builtin_amdgcn_mfma_f32_16x16x32_bf16(af, bfrag, zf, 0, 0, 0);
    const int c0 = cf * 16 + kg * 4;
    const unsigned lo = f2bf(d[0]) | ((unsigned)f2bf(d[1]) << 16);
    const unsigned hi = f2bf(d[2]) | ((unsigned)f2bf(d[3]) << 16);
    *(uint2*)&htile[el][c0] = make_uint2(lo, hi);
  }
  __syncthreads();

  // ---- A2: pre = htile + Pd + Ps + b1 -> LN -> SiLU -> htile (in place) ----
  {
    float pre[32];
    const uint4* hp = (const uint4*)&htile[e2][cg * 32];
    uint4 HV[4] = {hp[0], hp[1], hp[2], hp[3]};
    float s1 = 0.0f, s2 = 0.0f;
#pragma unroll
    for (int q = 0; q < 4; ++q) {
      const unsigned hx[4] = {HV[q].x, HV[q].y, HV[q].z, HV[q].w};
      const unsigned px[4] = {PV[q].x, PV[q].y, PV[q].z, PV[q].w};
      const unsigned sx[4] = {SV[q].x, SV[q].y, SV[q].z, SV[q].w};
#pragma unroll
      for (int j2 = 0; j2 < 4; ++j2) {
        const int idx = q * 8 + j2 * 2;
        const float v0 = bf2f(hx[j2] & 0xffffu) + bf2f(px[j2] & 0xffffu) +
                         bf2f(sx[j2] & 0xffffu) + b1s[cg * 32 + idx];
        const float v1 = bf2f(hx[j2] >> 16) + bf2f(px[j2] >> 16) +
                         bf2f(sx[j2] >> 16) + b1s[cg * 32 + idx + 1];
        pre[idx] = v0; pre[idx + 1] = v1;
        s1 += v0 + v1; s2 += v0 * v0 + v1 * v1;
      }
    }
    s1 += __shfl_xor(s1, 1); s2 += __shfl_xor(s2, 1);
    s1 += __shfl_xor(s1, 2); s2 += __shfl_xor(s2, 2);
    const float m = s1 * (1.0f / 128.0f);
    const float var = s2 * (1.0f / 128.0f) - m * m;
    const float rstd = rsqrtf(var + 1e-5f);
#pragma unroll
    for (int q = 0; q < 4; ++q) {
      unsigned ow[4];
#pragma unroll
      for (int j2 = 0; j2 < 4; ++j2) {
        const int idx = q * 8 + j2 * 2;
        float y0 = g1s[cg * 32 + idx] * ((pre[idx] - m) * rstd) + bb1s[cg * 32 + idx];
        float y1 = g1s[cg * 32 + idx + 1] * ((pre[idx + 1] - m) * rstd) + bb1s[cg * 32 + idx + 1];
        y0 = y0 * sigm(y0); y1 = y1 * sigm(y1);
        ow[j2] = f2bf(y0) | ((unsigned)f2bf(y1) << 16);
      }
      *(uint4*)&htile[e2][cg * 32 + q * 8] = make_uint4(ow[0], ow[1], ow[2], ow[3]);
    }
  }
  __syncthreads();

  // ---- B: msg^T = W2^T-frags x h-frags; lane holds 4 consecutive cols of one edge ----
  f32x4 acc[8];
#pragma unroll
  for (int cf = 0; cf < 8; ++cf) acc[cf] = zf;
#pragma unroll
  for (int ks = 0; ks < 4; ++ks) {
    const bf16x8 hb = *(const bf16x8*)&htile[w * 16 + li][ks * 32 + kg * 8];
#pragma unroll
    for (int cf = 0; cf < 8; ++cf) {
      const bf16x8 wf = *(const bf16x8*)(W2f + (size_t)((cf << 2) | ks) * 512 + lane * 8);
      acc[cf] = __builtin_amdgcn_mfma_f32_16x16x32_bf16(wf, hb, acc[cf], 0, 0, 0);
    }
  }

  // ---- C: scatter-add (b2 folded into k3) ----
  const int dstE = dsts[w * 16 + li];
  float* sp = sums + (size_t)dstE * 128 + kg * 4;
#pragma unroll
  for (int cf = 0; cf < 8; ++cf) {
    atomicAdd(sp + cf * 16 + 0, acc[cf][0]);
    atomicAdd(sp + cf * 16 + 1, acc[cf][1]);
    atomicAdd(sp + cf * 16 + 2, acc[cf][2]);
    atomicAdd(sp + cf * 16 + 3, acc[cf][3]);
  }
  if (t < 64) atomicAdd(cnt + dsts[t], 1.0f);
}

// ============ K3: GRU + LN2 (MFMA), 16 nodes per block ============
__global__ __launch_bounds__(256) void k3_gru(const float* __restrict__ x,
                                              const float* __restrict__ sums,
                                              const float* __restrict__ cnt,
                                              const unsigned short* __restrict__ Wihf,
                                              const unsigned short* __restrict__ Whhf,
                                              const float* __restrict__ bih,
                                              const float* __restrict__ bhh,
                                              const float* __restrict__ b2,
                                              const float* __restrict__ ln2g,
                                              const float* __restrict__ ln2b,
                                              float* __restrict__ out) {
  __shared__ unsigned short aggb[16][136];   // agg bf16
  __shared__ unsigned short Ss[16][776];     // [gi(384) | gh(384)] bf16, stride 1552B = 97*16
  const int t = threadIdx.x, lane = t & 63, w = t >> 6;
  const int kg = lane >> 4, li = lane & 15;
  const int n0 = blockIdx.x * 16;   // 3125*16 = 50000 exact

  // stage agg = sums/max(cnt,1) + (cnt>0)*b2
  {
    const int nl = t >> 4, c0 = (t & 15) * 8;
    const int gn = n0 + nl;
    const float c = cnt[gn];
    const float inv = 1.0f / fmaxf(c, 1.0f);
    const float bsc = (c > 0.0f) ? 1.0f : 0.0f;
    const float* sp = sums + (size_t)gn * 128 + c0;
    const float4 u = *(const float4*)sp, v = *(const float4*)(sp + 4);
    const float4 bu = *(const float4*)(b2 + c0), bv = *(const float4*)(b2 + c0 + 4);
    const unsigned o0 = f2bf(u.x * inv + bsc * bu.x) | ((unsigned)f2bf(u.y * inv + bsc * bu.y) << 16);
    const unsigned o1 = f2bf(u.z * inv + bsc * bu.z) | ((unsigned)f2bf(u.w * inv + bsc * bu.w) << 16);
    const unsigned o2 = f2bf(v.x * inv + bsc * bv.x) | ((unsigned)f2bf(v.y * inv + bsc * bv.y) << 16);
    const unsigned o3 = f2bf(v.z * inv + bsc * bv.z) | ((unsigned)f2bf(v.w * inv + bsc * bv.w) << 16);
    *(uint4*)&aggb[nl][c0] = make_uint4(o0, o1, o2, o3);
  }
  __syncthreads();

  // waves 0-1: gi = agg@Wih^T (coltiles 0..23); waves 2-3: gh = x@Whh^T
  const int isH = w >> 1;
  const int ctbase = (w & 1) * 12;
  const unsigned short* Wf = isH ? Whhf : Wihf;
  const float* bias = isH ? bhh : bih;
  const f32x4 zf = {0.0f, 0.0f, 0.0f, 0.0f};
  f32x4 acc[12];
#pragma unroll
  for (int i = 0; i < 12; ++i) acc[i] = zf;
#pragma unroll
  for (int ks = 0; ks < 4; ++ks) {
    bf16x8 bfrag;
    if (isH) {
      const float* xp = x + (size_t)(n0 + li) * 128 + ks * 32 + kg * 8;
      const float4 u = *(const float4*)xp, v = *(const float4*)(xp + 4);
      bfrag = pack8(u.x, u.y, u.z, u.w, v.x, v.y, v.z, v.w);
    } else {
      bfrag = *(const bf16x8*)&aggb[li][ks * 32 + kg * 8];
    }
#pragma unroll
    for (int i = 0; i < 12; ++i) {
      const int ct = ctbase + i;
      const bf16x8 af = *(const bf16x8*)(Wf + (size_t)(ct * 4 + ks) * 512 + lane * 8);
      acc[i] = __builtin_amdgcn_mfma_f32_16x16x32_bf16(af, bfrag, acc[i], 0, 0, 0);
    }
  }
#pragma unroll
  for (int i = 0; i < 12; ++i) {
    const int ocol = (ctbase + i) * 16 + kg * 4;
    const float4 bb = *(const float4*)(bias + ocol);
    const int col = isH * 384 + ocol;
    const unsigned lo = f2bf(acc[i][0] + bb.x) | ((unsigned)f2bf(acc[i][1] + bb.y) << 16);
    const unsigned hi = f2bf(acc[i][2] + bb.z) | ((unsigned)f2bf(acc[i][3] + bb.w) << 16);
    *(uint2*)&Ss[li][col] = make_uint2(lo, hi);
  }
  __syncthreads();

  // gates + residual + LN2
  const int nl = t >> 4, q0 = (t & 15) * 8;
  const int gn = n0 + nl;
  float xv[8];
  *(float4*)&xv[0] = *(const float4*)(x + (size_t)gn * 128 + q0);
  *(float4*)&xv[4] = *(const float4*)(x + (size_t)gn * 128 + q0 + 4);
  const uint4 gir = *(const uint4*)&Ss[nl][q0];
  const uint4 giz = *(const uint4*)&Ss[nl][q0 + 128];
  const uint4 gin = *(const uint4*)&Ss[nl][q0 + 256];
  const uint4 ghr = *(const uint4*)&Ss[nl][q0 + 384];
  const uint4 ghz = *(const uint4*)&Ss[nl][q0 + 512];
  const uint4 ghn = *(const uint4*)&Ss[nl][q0 + 640];
  const unsigned GIR[4] = {gir.x, gir.y, gir.z, gir.w};
  const unsigned GIZ[4] = {giz.x, giz.y, giz.z, giz.w};
  const unsigned GIN[4] = {gin.x, gin.y, gin.z, gin.w};
  const unsigned GHR[4] = {ghr.x, ghr.y, ghr.z, ghr.w};
  const unsigned GHZ[4] = {ghz.x, ghz.y, ghz.z, ghz.w};
  const unsigned GHN[4] = {ghn.x, ghn.y, ghn.z, ghn.w};
  float vb[8];
  float s1 = 0.0f, s2 = 0.0f;
#pragma unroll
  for (int j2 = 0; j2 < 4; ++j2) {
#pragma unroll
    for (int hl = 0; hl < 2; ++hl) {
      const int jj = j2 * 2 + hl;
      const unsigned sh = hl * 16;
      const float girv = bf2f((GIR[j2] >> sh) & 0xffffu);
      const float gizv = bf2f((GIZ[j2] >> sh) & 0xffffu);
      const float ginv = bf2f((GIN[j2] >> sh) & 0xffffu);
      const float ghrv = bf2f((GHR[j2] >> sh) & 0xffffu);
      const float ghzv = bf2f((GHZ[j2] >> sh) & 0xffffu);
      const float ghnv = bf2f((GHN[j2] >> sh) & 0xffffu);
      const float r = sigm(girv + ghrv);
      const float z = sigm(gizv + ghzv);
      const float nv = tanhf(ginv + r * ghnv);
      const float v = xv[jj] + (1.0f - z) * nv + z * xv[jj];
      vb[jj] = v; s1 += v; s2 += v * v;
    }
  }
  s1 += __shfl_xor(s1, 1); s2 += __shfl_xor(s2, 1);
  s1 += __shfl_xor(s1, 2); s2 += __shfl_xor(s2, 2);
  s1 += __shfl_xor(s1, 4); s2 += __shfl_xor(s2, 4);
  s1 += __shfl_xor(s1, 8); s2 += __shfl_xor(s2, 8);
  const float m = s1 * (1.0f / 128.0f);
  const float var = s2 * (1.0f / 128.0f) - m * m;
  const float rstd = rsqrtf(var + 1e-5f);
  float ov[8];
#pragma unroll
  for (int j = 0; j < 8; ++j)
    ov[j] = ln2g[q0 + j] * ((vb[j] - m) * rstd) + ln2b[q0 + j];
  *(float4*)(out + (size_t)gn * 128 + q0) = make_float4(ov[0], ov[1], ov[2], ov[3]);
  *(float4*)(out + (size_t)gn * 128 + q0 + 4) = make_float4(ov[4], ov[5], ov[6], ov[7]);
}

extern "C" void kernel_launch(void* const* d_in, const int* in_sizes, int n_in,
                              void* d_out, int out_size, void* d_ws, size_t ws_size,
                              hipStream_t stream) {
  const float* x         = (const float*)d_in[0];
  const float* edge_attr = (const float*)d_in[1];
  const float* pos       = (const float*)d_in[2];
  const float* W1        = (const float*)d_in[3];
  const float* b1        = (const float*)d_in[4];
  const float* ln1g      = (const float*)d_in[5];
  const float* ln1b      = (const float*)d_in[6];
  const float* W2        = (const float*)d_in[7];
  const float* b2        = (const float*)d_in[8];
  const float* Wih       = (const float*)d_in[9];
  const float* bih       = (const float*)d_in[10];
  const float* Whh       = (const float*)d_in[11];
  const float* bhh       = (const float*)d_in[12];
  const float* ln2g      = (const float*)d_in[13];
  const float* ln2b      = (const float*)d_in[14];
  const int*   ei        = (const int*)d_in[15];
  float* out = (float*)d_out;

  // ws layout (bytes): sums f32 [0, 25.6M) ; cnt f32 [25.6M, 25.8M) ;
  // P bf16 [25.8M, 51.4M) ; frags bf16 [51.4M, ...)
  float* sums = (float*)d_ws;
  float* cnt  = (float*)((char*)d_ws + 25600000);
  unsigned short* Pb    = (unsigned short*)((char*)d_ws + 25800000);
  unsigned short* frags = (unsigned short*)((char*)d_ws + 51400000);
  unsigned short* W1ef = frags;               // 8 frags
  unsigned short* W2f  = frags + 8 * 512;     // 32 frags
  unsigned short* W1nf = frags + 40 * 512;    // 64 frags
  unsigned short* Wihf = frags + 104 * 512;   // 96 frags
  unsigned short* Whhf = frags + 200 * 512;   // 96 frags

  hipMemsetAsync(sums, 0, (size_t)(NN * 128 + NN) * sizeof(float), stream);
  k0_prep<<<296, 64, 0, stream>>>(W1, W2, Wih, Whh, frags);
  k1_node_pre<<<3125, 256, 0, stream>>>(x, W1nf, Pb);
  k2_edge<<<12500, 256, 0, stream>>>(Pb, edge_attr, pos, ei, W1ef, W2f,
                                     b1, ln1g, ln1b, sums, cnt);
  k3_gru<<<3125, 256, 0, stream>>>(x, sums, cnt, Wihf, Whhf, bih, bhh, b2,
                                   ln2g, ln2b, out);
}

// Round 3
// 472.276 us; speedup vs baseline: 3.1688x; 3.1688x over previous
//
#include <hip/hip_runtime.h>
#include <math.h>

#define NN 50000
#define EE 800000

typedef __attribute__((ext_vector_type(8))) short bf16x8;
typedef __attribute__((ext_vector_type(4))) float f32x4;

__device__ __forceinline__ unsigned short f2bf(float f) {
  union { float f; unsigned u; } z; z.f = f;
  return (unsigned short)((z.u + 0x7fffu + ((z.u >> 16) & 1u)) >> 16);
}
__device__ __forceinline__ float bf2f(unsigned int h16) {
  union { unsigned u; float f; } z; z.u = h16 << 16; return z.f;
}
__device__ __forceinline__ float sigm(float v) { return 1.0f / (1.0f + __expf(-v)); }

__device__ __forceinline__ bf16x8 pack8(float a0, float a1, float a2, float a3,
                                        float a4, float a5, float a6, float a7) {
  bf16x8 r;
  r[0] = (short)f2bf(a0); r[1] = (short)f2bf(a1);
  r[2] = (short)f2bf(a2); r[3] = (short)f2bf(a3);
  r[4] = (short)f2bf(a4); r[5] = (short)f2bf(a5);
  r[6] = (short)f2bf(a6); r[7] = (short)f2bf(a7);
  return r;
}

// ============ K0: pack all weights into bf16 MFMA A-fragments ============
__global__ __launch_bounds__(64) void k0_prep(const float* __restrict__ W1,
                                              const float* __restrict__ W2,
                                              const float* __restrict__ Wih,
                                              const float* __restrict__ Whh,
                                              unsigned short* __restrict__ frags) {
  const int f = blockIdx.x, l = threadIdx.x;
  const int c16 = l & 15, kg = l >> 4;
  float v[8];
  if (f < 8) {
    const int c = f * 16 + c16;
#pragma unroll
    for (int j = 0; j < 8; ++j) {
      const int k = kg * 8 + j;
      v[j] = (k < 20) ? W1[(256 + k) * 128 + c] : 0.0f;
    }
  } else if (f < 40) {
    const int lf = f - 8, ct = lf >> 2, ks = lf & 3, c = ct * 16 + c16;
#pragma unroll
    for (int j = 0; j < 8; ++j) { const int k = ks * 32 + kg * 8 + j; v[j] = W2[k * 128 + c]; }
  } else if (f < 104) {
    const int lf = f - 40, ct = lf >> 2, ks = lf & 3, c = ct * 16 + c16;
#pragma unroll
    for (int j = 0; j < 8; ++j) {
      const int k = ks * 32 + kg * 8 + j;
      v[j] = (c < 128) ? W1[k * 128 + c] : W1[(128 + k) * 128 + (c - 128)];
    }
  } else if (f < 200) {
    const int lf = f - 104, ct = lf >> 2, ks = lf & 3, c = ct * 16 + c16;
#pragma unroll
    for (int j = 0; j < 8; ++j) { const int k = ks * 32 + kg * 8 + j; v[j] = Wih[c * 128 + k]; }
  } else {
    const int lf = f - 200, ct = lf >> 2, ks = lf & 3, c = ct * 16 + c16;
#pragma unroll
    for (int j = 0; j < 8; ++j) { const int k = ks * 32 + kg * 8 + j; v[j] = Whh[c * 128 + k]; }
  }
  *(bf16x8*)(frags + (size_t)f * 512 + l * 8) =
      pack8(v[0], v[1], v[2], v[3], v[4], v[5], v[6], v[7]);
}

// ============ K1: P[n][0:256] = x @ [W1_dst | W1_src]  (bf16 out) ============
__global__ __launch_bounds__(256) void k1_node_pre(const float* __restrict__ x,
                                                   const unsigned short* __restrict__ W1nf,
                                                   unsigned short* __restrict__ P) {
  const int t = threadIdx.x, lane = t & 63, w = t >> 6;
  const int kg = lane >> 4, li = lane & 15;
  const int node = blockIdx.x * 16 + li;   // 3125*16 = 50000 exact
  const f32x4 zf = {0.0f, 0.0f, 0.0f, 0.0f};
  f32x4 acc[4] = {zf, zf, zf, zf};
#pragma unroll
  for (int ks = 0; ks < 4; ++ks) {
    const float* xp = x + (size_t)node * 128 + ks * 32 + kg * 8;
    const float4 u = *(const float4*)xp, v = *(const float4*)(xp + 4);
    const bf16x8 xb = pack8(u.x, u.y, u.z, u.w, v.x, v.y, v.z, v.w);
#pragma unroll
    for (int i = 0; i < 4; ++i) {
      const int ct = w * 4 + i;
      const bf16x8 af = *(const bf16x8*)(W1nf + (size_t)(ct * 4 + ks) * 512 + lane * 8);
      acc[i] = __builtin_amdgcn_mfma_f32_16x16x32_bf16(af, xb, acc[i], 0, 0, 0);
    }
  }
#pragma unroll
  for (int i = 0; i < 4; ++i) {
    const int c0 = (w * 4 + i) * 16 + kg * 4;
    const unsigned lo = f2bf(acc[i][0]) | ((unsigned)f2bf(acc[i][1]) << 16);
    const unsigned hi = f2bf(acc[i][2]) | ((unsigned)f2bf(acc[i][3]) << 16);
    *(uint2*)(P + (size_t)node * 256 + c0) = make_uint2(lo, hi);
  }
}

// ============ K2: fused edge kernel (MFMA + coalesced scatter) ============
__global__ __launch_bounds__(256) void k2_edge(const unsigned short* __restrict__ P,
                                               const float* __restrict__ edge_attr,
                                               const float* __restrict__ pos,
                                               const int* __restrict__ ei,
                                               const unsigned short* __restrict__ W1ef,
                                               const unsigned short* __restrict__ W2f,
                                               const float* __restrict__ b1,
                                               const float* __restrict__ ln1g,
                                               const float* __restrict__ ln1b,
                                               float* __restrict__ sums,
                                               float* __restrict__ cnt) {
  __shared__ unsigned short htile[64][136];   // h (bf16), later reused for msg (bf16)
  __shared__ float4 relv[64];
  __shared__ int dsts[64], srcs[64];
  __shared__ float b1s[128], g1s[128], bb1s[128];

  const int t = threadIdx.x, lane = t & 63, w = t >> 6;
  const int kg = lane >> 4, li = lane & 15;
  const int e0 = blockIdx.x * 64;   // 12500*64 = 800000 exact

  if (t < 128) { b1s[t] = b1[t]; g1s[t] = ln1g[t]; bb1s[t] = ln1b[t]; }
  if (t < 64) {
    const int e = e0 + t;
    const int s = ei[e], d = ei[EE + e];
    srcs[t] = s; dsts[t] = d;
    const float rx = (pos[3 * s + 0] - pos[3 * d + 0]) * 0.2f;
    const float ry = (pos[3 * s + 1] - pos[3 * d + 1]) * 0.2f;
    const float rz = (pos[3 * s + 2] - pos[3 * d + 2]) * 0.2f;
    relv[t] = make_float4(rx, ry, rz, rx * rx + ry * ry + rz * rz);
  }
  __syncthreads();

  // issue P gathers early (A2 mapping: 4 threads per edge, 32 cols each)
  const int e2 = t >> 2, cg = t & 3;
  const int dn = dsts[e2], sn = srcs[e2];
  const uint4* pdp = (const uint4*)(P + (size_t)dn * 256 + cg * 32);
  const uint4* psp = (const uint4*)(P + (size_t)sn * 256 + 128 + cg * 32);
  uint4 PV[4] = {pdp[0], pdp[1], pdp[2], pdp[3]};
  uint4 SV[4] = {psp[0], psp[1], psp[2], psp[3]};

  // ---- A1: pre_edgepart = (ea|geom) @ W1[256:276]  via MFMA (transposed D) ----
  const int el = w * 16 + li;
  bf16x8 bfrag;
  if (kg == 0 || kg == 1) {
    const float* ep = edge_attr + (size_t)(e0 + el) * 16 + kg * 8;
    const float4 u = *(const float4*)ep, v = *(const float4*)(ep + 4);
    bfrag = pack8(u.x, u.y, u.z, u.w, v.x, v.y, v.z, v.w);
  } else if (kg == 2) {
    const float4 rv = relv[el];
    bfrag = pack8(rv.x, rv.y, rv.z, rv.w, 0.f, 0.f, 0.f, 0.f);
  } else {
    bfrag = pack8(0.f, 0.f, 0.f, 0.f, 0.f, 0.f, 0.f, 0.f);
  }
  const f32x4 zf = {0.0f, 0.0f, 0.0f, 0.0f};
#pragma unroll
  for (int cf = 0; cf < 8; ++cf) {
    const bf16x8 af = *(const bf16x8*)(W1ef + (size_t)cf * 512 + lane * 8);
    const f32x4 d = __builtin_amdgcn_mfma_f32_16x16x32_bf16(af, bfrag, zf, 0, 0, 0);
    const int c0 = cf * 16 + kg * 4;
    const unsigned lo = f2bf(d[0]) | ((unsigned)f2bf(d[1]) << 16);
    const unsigned hi = f2bf(d[2]) | ((unsigned)f2bf(d[3]) << 16);
    *(uint2*)&htile[el][c0] = make_uint2(lo, hi);
  }
  __syncthreads();

  // ---- A2: pre = htile + Pd + Ps + b1 -> LN -> SiLU -> htile (in place) ----
  {
    float pre[32];
    const uint4* hp = (const uint4*)&htile[e2][cg * 32];
    uint4 HV[4] = {hp[0], hp[1], hp[2], hp[3]};
    float s1 = 0.0f, s2 = 0.0f;
#pragma unroll
    for (int q = 0; q < 4; ++q) {
      const unsigned hx[4] = {HV[q].x, HV[q].y, HV[q].z, HV[q].w};
      const unsigned px[4] = {PV[q].x, PV[q].y, PV[q].z, PV[q].w};
      const unsigned sx[4] = {SV[q].x, SV[q].y, SV[q].z, SV[q].w};
#pragma unroll
      for (int j2 = 0; j2 < 4; ++j2) {
        const int idx = q * 8 + j2 * 2;
        const float v0 = bf2f(hx[j2] & 0xffffu) + bf2f(px[j2] & 0xffffu) +
                         bf2f(sx[j2] & 0xffffu) + b1s[cg * 32 + idx];
        const float v1 = bf2f(hx[j2] >> 16) + bf2f(px[j2] >> 16) +
                         bf2f(sx[j2] >> 16) + b1s[cg * 32 + idx + 1];
        pre[idx] = v0; pre[idx + 1] = v1;
        s1 += v0 + v1; s2 += v0 * v0 + v1 * v1;
      }
    }
    s1 += __shfl_xor(s1, 1); s2 += __shfl_xor(s2, 1);
    s1 += __shfl_xor(s1, 2); s2 += __shfl_xor(s2, 2);
    const float m = s1 * (1.0f / 128.0f);
    const float var = s2 * (1.0f / 128.0f) - m * m;
    const float rstd = rsqrtf(var + 1e-5f);
#pragma unroll
    for (int q = 0; q < 4; ++q) {
      unsigned ow[4];
#pragma unroll
      for (int j2 = 0; j2 < 4; ++j2) {
        const int idx = q * 8 + j2 * 2;
        float y0 = g1s[cg * 32 + idx] * ((pre[idx] - m) * rstd) + bb1s[cg * 32 + idx];
        float y1 = g1s[cg * 32 + idx + 1] * ((pre[idx + 1] - m) * rstd) + bb1s[cg * 32 + idx + 1];
        y0 = y0 * sigm(y0); y1 = y1 * sigm(y1);
        ow[j2] = f2bf(y0) | ((unsigned)f2bf(y1) << 16);
      }
      *(uint4*)&htile[e2][cg * 32 + q * 8] = make_uint4(ow[0], ow[1], ow[2], ow[3]);
    }
  }
  __syncthreads();

  // ---- B: stage h-frags in regs, MFMA msg^T, write msg (bf16) back to htile ----
  {
    bf16x8 hfr[4];
#pragma unroll
    for (int ks = 0; ks < 4; ++ks)
      hfr[ks] = *(const bf16x8*)&htile[w * 16 + li][ks * 32 + kg * 8];

    f32x4 acc[8];
#pragma unroll
    for (int cf = 0; cf < 8; ++cf) acc[cf] = zf;
#pragma unroll
    for (int ks = 0; ks < 4; ++ks) {
#pragma unroll
      for (int cf = 0; cf < 8; ++cf) {
        const bf16x8 wf = *(const bf16x8*)(W2f + (size_t)((cf << 2) | ks) * 512 + lane * 8);
        acc[cf] = __builtin_amdgcn_mfma_f32_16x16x32_bf16(wf, hfr[ks], acc[cf], 0, 0, 0);
      }
    }
    // write msg back into htile (bf16); every write data-depends on all reads above
#pragma unroll
    for (int cf = 0; cf < 8; ++cf) {
      const int c0 = cf * 16 + kg * 4;
      const unsigned lo = f2bf(acc[cf][0]) | ((unsigned)f2bf(acc[cf][1]) << 16);
      const unsigned hi = f2bf(acc[cf][2]) | ((unsigned)f2bf(acc[cf][3]) << 16);
      *(uint2*)&htile[w * 16 + li][c0] = make_uint2(lo, hi);
    }
  }
  __syncthreads();

  // ---- C: coalesced scatter: 32 lanes = 32 consecutive cols of one dst row ----
  {
    const int eg = t >> 5;            // 0..7 (half-wave groups)
    const int ng = t & 31;
#pragma unroll
    for (int i = 0; i < 8; ++i) {
      const int ee = eg * 8 + i;
      float* sp = sums + (size_t)dsts[ee] * 128;
#pragma unroll
      for (int jn = 0; jn < 4; ++jn) {
        const int c = ng + 32 * jn;
        atomicAdd(sp + c, bf2f((unsigned)htile[ee][c]));
      }
    }
  }
  if (t < 64) atomicAdd(cnt + dsts[t], 1.0f);
}

// ============ K3: GRU + LN2 (MFMA), 16 nodes per block ============
__global__ __launch_bounds__(256) void k3_gru(const float* __restrict__ x,
                                              const float* __restrict__ sums,
                                              const float* __restrict__ cnt,
                                              const unsigned short* __restrict__ Wihf,
                                              const unsigned short* __restrict__ Whhf,
                                              const float* __restrict__ bih,
                                              const float* __restrict__ bhh,
                                              const float* __restrict__ b2,
                                              const float* __restrict__ ln2g,
                                              const float* __restrict__ ln2b,
                                              float* __restrict__ out) {
  __shared__ unsigned short aggb[16][136];   // agg bf16
  __shared__ unsigned short Ss[16][776];     // [gi(384) | gh(384)] bf16
  const int t = threadIdx.x, lane = t & 63, w = t >> 6;
  const int kg = lane >> 4, li = lane & 15;
  const int n0 = blockIdx.x * 16;   // 3125*16 = 50000 exact

  // stage agg = sums/max(cnt,1) + (cnt>0)*b2
  {
    const int nl = t >> 4, c0 = (t & 15) * 8;
    const int gn = n0 + nl;
    const float c = cnt[gn];
    const float inv = 1.0f / fmaxf(c, 1.0f);
    const float bsc = (c > 0.0f) ? 1.0f : 0.0f;
    const float* sp = sums + (size_t)gn * 128 + c0;
    const float4 u = *(const float4*)sp, v = *(const float4*)(sp + 4);
    const float4 bu = *(const float4*)(b2 + c0), bv = *(const float4*)(b2 + c0 + 4);
    const unsigned o0 = f2bf(u.x * inv + bsc * bu.x) | ((unsigned)f2bf(u.y * inv + bsc * bu.y) << 16);
    const unsigned o1 = f2bf(u.z * inv + bsc * bu.z) | ((unsigned)f2bf(u.w * inv + bsc * bu.w) << 16);
    const unsigned o2 = f2bf(v.x * inv + bsc * bv.x) | ((unsigned)f2bf(v.y * inv + bsc * bv.y) << 16);
    const unsigned o3 = f2bf(v.z * inv + bsc * bv.z) | ((unsigned)f2bf(v.w * inv + bsc * bv.w) << 16);
    *(uint4*)&aggb[nl][c0] = make_uint4(o0, o1, o2, o3);
  }
  __syncthreads();

  // waves 0-1: gi = agg@Wih^T ; waves 2-3: gh = x@Whh^T
  const int isH = w >> 1;
  const int ctbase = (w & 1) * 12;
  const unsigned short* Wf = isH ? Whhf : Wihf;
  const float* bias = isH ? bhh : bih;
  const f32x4 zf = {0.0f, 0.0f, 0.0f, 0.0f};
  f32x4 acc[12];
#pragma unroll
  for (int i = 0; i < 12; ++i) acc[i] = zf;
#pragma unroll
  for (int ks = 0; ks < 4; ++ks) {
    bf16x8 bfrag;
    if (isH) {
      const float* xp = x + (size_t)(n0 + li) * 128 + ks * 32 + kg * 8;
      const float4 u = *(const float4*)xp, v = *(const float4*)(xp + 4);
      bfrag = pack8(u.x, u.y, u.z, u.w, v.x, v.y, v.z, v.w);
    } else {
      bfrag = *(const bf16x8*)&aggb[li][ks * 32 + kg * 8];
    }
#pragma unroll
    for (int i = 0; i < 12; ++i) {
      const int ct = ctbase + i;
      const bf16x8 af = *(const bf16x8*)(Wf + (size_t)(ct * 4 + ks) * 512 + lane * 8);
      acc[i] = __builtin_amdgcn_mfma_f32_16x16x32_bf16(af, bfrag, acc[i], 0, 0, 0);
    }
  }
#pragma unroll
  for (int i = 0; i < 12; ++i) {
    const int ocol = (ctbase + i) * 16 + kg * 4;
    const float4 bb = *(const float4*)(bias + ocol);
    const int col = isH * 384 + ocol;
    const unsigned lo = f2bf(acc[i][0] + bb.x) | ((unsigned)f2bf(acc[i][1] + bb.y) << 16);
    const unsigned hi = f2bf(acc[i][2] + bb.z) | ((unsigned)f2bf(acc[i][3] + bb.w) << 16);
    *(uint2*)&Ss[li][col] = make_uint2(lo, hi);
  }
  __syncthreads();

  // gates + residual + LN2
  const int nl = t >> 4, q0 = (t & 15) * 8;
  const int gn = n0 + nl;
  float xv[8];
  *(float4*)&xv[0] = *(const float4*)(x + (size_t)gn * 128 + q0);
  *(float4*)&xv[4] = *(const float4*)(x + (size_t)gn * 128 + q0 + 4);
  const uint4 gir = *(const uint4*)&Ss[nl][q0];
  const uint4 giz = *(const uint4*)&Ss[nl][q0 + 128];
  const uint4 gin = *(const uint4*)&Ss[nl][q0 + 256];
  const uint4 ghr = *(const uint4*)&Ss[nl][q0 + 384];
  const uint4 ghz = *(const uint4*)&Ss[nl][q0 + 512];
  const uint4 ghn = *(const uint4*)&Ss[nl][q0 + 640];
  const unsigned GIR[4] = {gir.x, gir.y, gir.z, gir.w};
  const unsigned GIZ[4] = {giz.x, giz.y, giz.z, giz.w};
  const unsigned GIN[4] = {gin.x, gin.y, gin.z, gin.w};
  const unsigned GHR[4] = {ghr.x, ghr.y, ghr.z, ghr.w};
  const unsigned GHZ[4] = {ghz.x, ghz.y, ghz.z, ghz.w};
  const unsigned GHN[4] = {ghn.x, ghn.y, ghn.z, ghn.w};
  float vb[8];
  float s1 = 0.0f, s2 = 0.0f;
#pragma unroll
  for (int j2 = 0; j2 < 4; ++j2) {
#pragma unroll
    for (int hl = 0; hl < 2; ++hl) {
      const int jj = j2 * 2 + hl;
      const unsigned sh = hl * 16;
      const float girv = bf2f((GIR[j2] >> sh) & 0xffffu);
      const float gizv = bf2f((GIZ[j2] >> sh) & 0xffffu);
      const float ginv = bf2f((GIN[j2] >> sh) & 0xffffu);
      const float ghrv = bf2f((GHR[j2] >> sh) & 0xffffu);
      const float ghzv = bf2f((GHZ[j2] >> sh) & 0xffffu);
      const float ghnv = bf2f((GHN[j2] >> sh) & 0xffffu);
      const float r = sigm(girv + ghrv);
      const float z = sigm(gizv + ghzv);
      const float nv = tanhf(ginv + r * ghnv);
      const float v = xv[jj] + (1.0f - z) * nv + z * xv[jj];
      vb[jj] = v; s1 += v; s2 += v * v;
    }
  }
  s1 += __shfl_xor(s1, 1); s2 += __shfl_xor(s2, 1);
  s1 += __shfl_xor(s1, 2); s2 += __shfl_xor(s2, 2);
  s1 += __shfl_xor(s1, 4); s2 += __shfl_xor(s2, 4);
  s1 += __shfl_xor(s1, 8); s2 += __shfl_xor(s2, 8);
  const float m = s1 * (1.0f / 128.0f);
  const float var = s2 * (1.0f / 128.0f) - m * m;
  const float rstd = rsqrtf(var + 1e-5f);
  float ov[8];
#pragma unroll
  for (int j = 0; j < 8; ++j)
    ov[j] = ln2g[q0 + j] * ((vb[j] - m) * rstd) + ln2b[q0 + j];
  *(float4*)(out + (size_t)gn * 128 + q0) = make_float4(ov[0], ov[1], ov[2], ov[3]);
  *(float4*)(out + (size_t)gn * 128 + q0 + 4) = make_float4(ov[4], ov[5], ov[6], ov[7]);
}

extern "C" void kernel_launch(void* const* d_in, const int* in_sizes, int n_in,
                              void* d_out, int out_size, void* d_ws, size_t ws_size,
                              hipStream_t stream) {
  const float* x         = (const float*)d_in[0];
  const float* edge_attr = (const float*)d_in[1];
  const float* pos       = (const float*)d_in[2];
  const float* W1        = (const float*)d_in[3];
  const float* b1        = (const float*)d_in[4];
  const float* ln1g      = (const float*)d_in[5];
  const float* ln1b      = (const float*)d_in[6];
  const float* W2        = (const float*)d_in[7];
  const float* b2        = (const float*)d_in[8];
  const float* Wih       = (const float*)d_in[9];
  const float* bih       = (const float*)d_in[10];
  const float* Whh       = (const float*)d_in[11];
  const float* bhh       = (const float*)d_in[12];
  const float* ln2g      = (const float*)d_in[13];
  const float* ln2b      = (const float*)d_in[14];
  const int*   ei        = (const int*)d_in[15];
  float* out = (float*)d_out;

  float* sums = (float*)d_ws;
  float* cnt  = (float*)((char*)d_ws + 25600000);
  unsigned short* Pb    = (unsigned short*)((char*)d_ws + 25800000);
  unsigned short* frags = (unsigned short*)((char*)d_ws + 51400000);
  unsigned short* W1ef = frags;               // 8 frags
  unsigned short* W2f  = frags + 8 * 512;     // 32 frags
  unsigned short* W1nf = frags + 40 * 512;    // 64 frags
  unsigned short* Wihf = frags + 104 * 512;   // 96 frags
  unsigned short* Whhf = frags + 200 * 512;   // 96 frags

  hipMemsetAsync(sums, 0, (size_t)(NN * 128 + NN) * sizeof(float), stream);
  k0_prep<<<296, 64, 0, stream>>>(W1, W2, Wih, Whh, frags);
  k1_node_pre<<<3125, 256, 0, stream>>>(x, W1nf, Pb);
  k2_edge<<<12500, 256, 0, stream>>>(Pb, edge_attr, pos, ei, W1ef, W2f,
                                     b1, ln1g, ln1b, sums, cnt);
  k3_gru<<<3125, 256, 0, stream>>>(x, sums, cnt, Wihf, Whhf, bih, bhh, b2,
                                   ln2g, ln2b, out);
}

// Round 4
// 334.092 us; speedup vs baseline: 4.4795x; 1.4136x over previous
//
#include <hip/hip_runtime.h>
#include <math.h>

#define NN 50000
#define EE 800000

typedef __attribute__((ext_vector_type(8))) short bf16x8;
typedef __attribute__((ext_vector_type(4))) float f32x4;

__device__ __forceinline__ unsigned short f2bf(float f) {
  union { float f; unsigned u; } z; z.f = f;
  return (unsigned short)((z.u + 0x7fffu + ((z.u >> 16) & 1u)) >> 16);
}
__device__ __forceinline__ float bf2f(unsigned int h16) {
  union { unsigned u; float f; } z; z.u = h16 << 16; return z.f;
}
__device__ __forceinline__ float sigm(float v) { return 1.0f / (1.0f + __expf(-v)); }

__device__ __forceinline__ bf16x8 pack8(float a0, float a1, float a2, float a3,
                                        float a4, float a5, float a6, float a7) {
  bf16x8 r;
  r[0] = (short)f2bf(a0); r[1] = (short)f2bf(a1);
  r[2] = (short)f2bf(a2); r[3] = (short)f2bf(a3);
  r[4] = (short)f2bf(a4); r[5] = (short)f2bf(a5);
  r[6] = (short)f2bf(a6); r[7] = (short)f2bf(a7);
  return r;
}

// ============ K0: pack all weights into bf16 MFMA A-fragments ============
__global__ __launch_bounds__(64) void k0_prep(const float* __restrict__ W1,
                                              const float* __restrict__ W2,
                                              const float* __restrict__ Wih,
                                              const float* __restrict__ Whh,
                                              unsigned short* __restrict__ frags) {
  const int f = blockIdx.x, l = threadIdx.x;
  const int c16 = l & 15, kg = l >> 4;
  float v[8];
  if (f < 8) {
    const int c = f * 16 + c16;
#pragma unroll
    for (int j = 0; j < 8; ++j) {
      const int k = kg * 8 + j;
      v[j] = (k < 20) ? W1[(256 + k) * 128 + c] : 0.0f;
    }
  } else if (f < 40) {
    const int lf = f - 8, ct = lf >> 2, ks = lf & 3, c = ct * 16 + c16;
#pragma unroll
    for (int j = 0; j < 8; ++j) { const int k = ks * 32 + kg * 8 + j; v[j] = W2[k * 128 + c]; }
  } else if (f < 104) {
    const int lf = f - 40, ct = lf >> 2, ks = lf & 3, c = ct * 16 + c16;
#pragma unroll
    for (int j = 0; j < 8; ++j) {
      const int k = ks * 32 + kg * 8 + j;
      v[j] = (c < 128) ? W1[k * 128 + c] : W1[(128 + k) * 128 + (c - 128)];
    }
  } else if (f < 200) {
    const int lf = f - 104, ct = lf >> 2, ks = lf & 3, c = ct * 16 + c16;
#pragma unroll
    for (int j = 0; j < 8; ++j) { const int k = ks * 32 + kg * 8 + j; v[j] = Wih[c * 128 + k]; }
  } else {
    const int lf = f - 200, ct = lf >> 2, ks = lf & 3, c = ct * 16 + c16;
#pragma unroll
    for (int j = 0; j < 8; ++j) { const int k = ks * 32 + kg * 8 + j; v[j] = Whh[c * 128 + k]; }
  }
  *(bf16x8*)(frags + (size_t)f * 512 + l * 8) =
      pack8(v[0], v[1], v[2], v[3], v[4], v[5], v[6], v[7]);
}

// ============ counting sort of edges by dst ============
__global__ __launch_bounds__(256) void k_hist(const int* __restrict__ ei,
                                              int* __restrict__ deg) {
  const int e = blockIdx.x * 256 + threadIdx.x;
  if (e < EE) atomicAdd(&deg[ei[EE + e]], 1);
}

__global__ __launch_bounds__(256) void kA_partial(const int* __restrict__ deg,
                                                  int* __restrict__ bsum) {
  const int i = blockIdx.x * 256 + threadIdx.x;
  int v = (i < NN) ? deg[i] : 0;
#pragma unroll
  for (int o = 32; o > 0; o >>= 1) v += __shfl_down(v, o);
  __shared__ int wsum[4];
  if ((threadIdx.x & 63) == 0) wsum[threadIdx.x >> 6] = v;
  __syncthreads();
  if (threadIdx.x == 0) bsum[blockIdx.x] = wsum[0] + wsum[1] + wsum[2] + wsum[3];
}

__global__ __launch_bounds__(256) void kB_scan(const int* __restrict__ bsum,
                                               int* __restrict__ boff) {
  __shared__ int s[256];
  const int t = threadIdx.x;
  const int orig = (t < 196) ? bsum[t] : 0;
  s[t] = orig;
  __syncthreads();
  for (int o = 1; o < 256; o <<= 1) {
    const int v = (t >= o) ? s[t - o] : 0;
    __syncthreads();
    s[t] += v;
    __syncthreads();
  }
  if (t < 196) boff[t] = s[t] - orig;
}

__global__ __launch_bounds__(256) void kC_offs(const int* __restrict__ deg,
                                               const int* __restrict__ boff,
                                               int* __restrict__ offs) {
  __shared__ int s[256];
  const int t = threadIdx.x, i = blockIdx.x * 256 + t;
  const int orig = (i < NN) ? deg[i] : 0;
  s[t] = orig;
  __syncthreads();
  for (int o = 1; o < 256; o <<= 1) {
    const int v = (t >= o) ? s[t - o] : 0;
    __syncthreads();
    s[t] += v;
    __syncthreads();
  }
  if (i < NN) offs[i] = boff[blockIdx.x] + s[t] - orig;
}

__global__ __launch_bounds__(256) void k_scatter(const int* __restrict__ ei,
                                                 const int* __restrict__ offs,
                                                 int* __restrict__ cur,
                                                 int* __restrict__ perm) {
  const int e = blockIdx.x * 256 + threadIdx.x;
  if (e < EE) {
    const int d = ei[EE + e];
    const int p = atomicAdd(&cur[d], 1);
    perm[offs[d] + p] = e;
  }
}

// ============ K1: P[n][0:256] = x @ [W1_dst | W1_src]  (bf16 out) ============
__global__ __launch_bounds__(256) void k1_node_pre(const float* __restrict__ x,
                                                   const unsigned short* __restrict__ W1nf,
                                                   unsigned short* __restrict__ P) {
  const int t = threadIdx.x, lane = t & 63, w = t >> 6;
  const int kg = lane >> 4, li = lane & 15;
  const int node = blockIdx.x * 16 + li;   // 3125*16 = 50000 exact
  const f32x4 zf = {0.0f, 0.0f, 0.0f, 0.0f};
  f32x4 acc[4] = {zf, zf, zf, zf};
#pragma unroll
  for (int ks = 0; ks < 4; ++ks) {
    const float* xp = x + (size_t)node * 128 + ks * 32 + kg * 8;
    const float4 u = *(const float4*)xp, v = *(const float4*)(xp + 4);
    const bf16x8 xb = pack8(u.x, u.y, u.z, u.w, v.x, v.y, v.z, v.w);
#pragma unroll
    for (int i = 0; i < 4; ++i) {
      const int ct = w * 4 + i;
      const bf16x8 af = *(const bf16x8*)(W1nf + (size_t)(ct * 4 + ks) * 512 + lane * 8);
      acc[i] = __builtin_amdgcn_mfma_f32_16x16x32_bf16(af, xb, acc[i], 0, 0, 0);
    }
  }
#pragma unroll
  for (int i = 0; i < 4; ++i) {
    const int c0 = (w * 4 + i) * 16 + kg * 4;
    const unsigned lo = f2bf(acc[i][0]) | ((unsigned)f2bf(acc[i][1]) << 16);
    const unsigned hi = f2bf(acc[i][2]) | ((unsigned)f2bf(acc[i][3]) << 16);
    *(uint2*)(P + (size_t)node * 256 + c0) = make_uint2(lo, hi);
  }
}

// ============ K2: fused edge kernel (MFMA + sorted segmented scatter) ============
__global__ __launch_bounds__(256) void k2_edge(const unsigned short* __restrict__ P,
                                               const float* __restrict__ edge_attr,
                                               const float* __restrict__ pos,
                                               const int* __restrict__ ei,
                                               const int* __restrict__ perm,
                                               const unsigned short* __restrict__ W1ef,
                                               const unsigned short* __restrict__ W2f,
                                               const float* __restrict__ b1,
                                               const float* __restrict__ ln1g,
                                               const float* __restrict__ ln1b,
                                               float* __restrict__ sums) {
  __shared__ unsigned short htile[64][136];   // h (bf16), later reused for msg (bf16)
  __shared__ float4 relv[64];
  __shared__ int dsts[64], srcs[64], eids[64];
  __shared__ float b1s[128], g1s[128], bb1s[128];

  const int t = threadIdx.x, lane = t & 63, w = t >> 6;
  const int kg = lane >> 4, li = lane & 15;
  const int e0 = blockIdx.x * 64;   // 12500*64 = 800000 exact

  if (t < 128) { b1s[t] = b1[t]; g1s[t] = ln1g[t]; bb1s[t] = ln1b[t]; }
  if (t < 64) {
    const int e = perm[e0 + t];
    eids[t] = e;
    const int s = ei[e], d = ei[EE + e];
    srcs[t] = s; dsts[t] = d;
    const float rx = (pos[3 * s + 0] - pos[3 * d + 0]) * 0.2f;
    const float ry = (pos[3 * s + 1] - pos[3 * d + 1]) * 0.2f;
    const float rz = (pos[3 * s + 2] - pos[3 * d + 2]) * 0.2f;
    relv[t] = make_float4(rx, ry, rz, rx * rx + ry * ry + rz * rz);
  }
  __syncthreads();

  // issue P gathers early (A2 mapping: 4 threads per edge, 32 cols each)
  const int e2 = t >> 2, cg = t & 3;
  const int dn = dsts[e2], sn = srcs[e2];
  const uint4* pdp = (const uint4*)(P + (size_t)dn * 256 + cg * 32);
  const uint4* psp = (const uint4*)(P + (size_t)sn * 256 + 128 + cg * 32);
  uint4 PV[4] = {pdp[0], pdp[1], pdp[2], pdp[3]};
  uint4 SV[4] = {psp[0], psp[1], psp[2], psp[3]};

  // ---- A1: pre_edgepart = (ea|geom) @ W1[256:276]  via MFMA (transposed D) ----
  const int el = w * 16 + li;
  bf16x8 bfrag;
  if (kg == 0 || kg == 1) {
    const float* ep = edge_attr + (size_t)eids[el] * 16 + kg * 8;
    const float4 u = *(const float4*)ep, v = *(const float4*)(ep + 4);
    bfrag = pack8(u.x, u.y, u.z, u.w, v.x, v.y, v.z, v.w);
  } else if (kg == 2) {
    const float4 rv = relv[el];
    bfrag = pack8(rv.x, rv.y, rv.z, rv.w, 0.f, 0.f, 0.f, 0.f);
  } else {
    bfrag = pack8(0.f, 0.f, 0.f, 0.f, 0.f, 0.f, 0.f, 0.f);
  }
  const f32x4 zf = {0.0f, 0.0f, 0.0f, 0.0f};
#pragma unroll
  for (int cf = 0; cf < 8; ++cf) {
    const bf16x8 af = *(const bf16x8*)(W1ef + (size_t)cf * 512 + lane * 8);
    const f32x4 d = __builtin_amdgcn_mfma_f32_16x16x32_bf16(af, bfrag, zf, 0, 0, 0);
    const int c0 = cf * 16 + kg * 4;
    const unsigned lo = f2bf(d[0]) | ((unsigned)f2bf(d[1]) << 16);
    const unsigned hi = f2bf(d[2]) | ((unsigned)f2bf(d[3]) << 16);
    *(uint2*)&htile[el][c0] = make_uint2(lo, hi);
  }
  __syncthreads();

  // ---- A2: pre = htile + Pd + Ps + b1 -> LN -> SiLU -> htile (in place) ----
  {
    float pre[32];
    const uint4* hp = (const uint4*)&htile[e2][cg * 32];
    uint4 HV[4] = {hp[0], hp[1], hp[2], hp[3]};
    float s1 = 0.0f, s2 = 0.0f;
#pragma unroll
    for (int q = 0; q < 4; ++q) {
      const unsigned hx[4] = {HV[q].x, HV[q].y, HV[q].z, HV[q].w};
      const unsigned px[4] = {PV[q].x, PV[q].y, PV[q].z, PV[q].w};
      const unsigned sx[4] = {SV[q].x, SV[q].y, SV[q].z, SV[q].w};
#pragma unroll
      for (int j2 = 0; j2 < 4; ++j2) {
        const int idx = q * 8 + j2 * 2;
        const float v0 = bf2f(hx[j2] & 0xffffu) + bf2f(px[j2] & 0xffffu) +
                         bf2f(sx[j2] & 0xffffu) + b1s[cg * 32 + idx];
        const float v1 = bf2f(hx[j2] >> 16) + bf2f(px[j2] >> 16) +
                         bf2f(sx[j2] >> 16) + b1s[cg * 32 + idx + 1];
        pre[idx] = v0; pre[idx + 1] = v1;
        s1 += v0 + v1; s2 += v0 * v0 + v1 * v1;
      }
    }
    s1 += __shfl_xor(s1, 1); s2 += __shfl_xor(s2, 1);
    s1 += __shfl_xor(s1, 2); s2 += __shfl_xor(s2, 2);
    const float m = s1 * (1.0f / 128.0f);
    const float var = s2 * (1.0f / 128.0f) - m * m;
    const float rstd = rsqrtf(var + 1e-5f);
#pragma unroll
    for (int q = 0; q < 4; ++q) {
      unsigned ow[4];
#pragma unroll
      for (int j2 = 0; j2 < 4; ++j2) {
        const int idx = q * 8 + j2 * 2;
        float y0 = g1s[cg * 32 + idx] * ((pre[idx] - m) * rstd) + bb1s[cg * 32 + idx];
        float y1 = g1s[cg * 32 + idx + 1] * ((pre[idx + 1] - m) * rstd) + bb1s[cg * 32 + idx + 1];
        y0 = y0 * sigm(y0); y1 = y1 * sigm(y1);
        ow[j2] = f2bf(y0) | ((unsigned)f2bf(y1) << 16);
      }
      *(uint4*)&htile[e2][cg * 32 + q * 8] = make_uint4(ow[0], ow[1], ow[2], ow[3]);
    }
  }
  __syncthreads();

  // ---- B: stage h-frags in regs, MFMA msg^T, write msg (bf16) back to htile ----
  {
    bf16x8 hfr[4];
#pragma unroll
    for (int ks = 0; ks < 4; ++ks)
      hfr[ks] = *(const bf16x8*)&htile[w * 16 + li][ks * 32 + kg * 8];

    f32x4 acc[8];
#pragma unroll
    for (int cf = 0; cf < 8; ++cf) acc[cf] = zf;
#pragma unroll
    for (int ks = 0; ks < 4; ++ks) {
#pragma unroll
      for (int cf = 0; cf < 8; ++cf) {
        const bf16x8 wf = *(const bf16x8*)(W2f + (size_t)((cf << 2) | ks) * 512 + lane * 8);
        acc[cf] = __builtin_amdgcn_mfma_f32_16x16x32_bf16(wf, hfr[ks], acc[cf], 0, 0, 0);
      }
    }
#pragma unroll
    for (int cf = 0; cf < 8; ++cf) {
      const int c0 = cf * 16 + kg * 4;
      const unsigned lo = f2bf(acc[cf][0]) | ((unsigned)f2bf(acc[cf][1]) << 16);
      const unsigned hi = f2bf(acc[cf][2]) | ((unsigned)f2bf(acc[cf][3]) << 16);
      *(uint2*)&htile[w * 16 + li][c0] = make_uint2(lo, hi);
    }
  }
  __syncthreads();

  // ---- C: segmented-run reduction over sorted dsts, coalesced flush ----
  {
    const int c = t & 127;            // column
    const int h0 = (t >> 7) * 32;     // edges h0..h0+31 (wave-uniform)
    int rd = dsts[h0];
    float racc = bf2f((unsigned)htile[h0][c]);
#pragma unroll
    for (int i = 1; i < 32; ++i) {
      const int ee = h0 + i;
      const int d = dsts[ee];
      const float v = bf2f((unsigned)htile[ee][c]);
      if (d == rd) {
        racc += v;
      } else {
        atomicAdd(sums + (size_t)rd * 128 + c, racc);
        rd = d; racc = v;
      }
    }
    atomicAdd(sums + (size_t)rd * 128 + c, racc);
  }
}

// ============ K3: GRU + LN2 (MFMA), 16 nodes per block ============
__global__ __launch_bounds__(256) void k3_gru(const float* __restrict__ x,
                                              const float* __restrict__ sums,
                                              const int* __restrict__ deg,
                                              const unsigned short* __restrict__ Wihf,
                                              const unsigned short* __restrict__ Whhf,
                                              const float* __restrict__ bih,
                                              const float* __restrict__ bhh,
                                              const float* __restrict__ b2,
                                              const float* __restrict__ ln2g,
                                              const float* __restrict__ ln2b,
                                              float* __restrict__ out) {
  __shared__ unsigned short aggb[16][136];   // agg bf16
  __shared__ unsigned short Ss[16][776];     // [gi(384) | gh(384)] bf16
  const int t = threadIdx.x, lane = t & 63, w = t >> 6;
  const int kg = lane >> 4, li = lane & 15;
  const int n0 = blockIdx.x * 16;   // 3125*16 = 50000 exact

  // stage agg = sums/max(deg,1) + (deg>0)*b2
  {
    const int nl = t >> 4, c0 = (t & 15) * 8;
    const int gn = n0 + nl;
    const int dc = deg[gn];
    const float inv = 1.0f / fmaxf((float)dc, 1.0f);
    const float bsc = (dc > 0) ? 1.0f : 0.0f;
    const float* sp = sums + (size_t)gn * 128 + c0;
    const float4 u = *(const float4*)sp, v = *(const float4*)(sp + 4);
    const float4 bu = *(const float4*)(b2 + c0), bv = *(const float4*)(b2 + c0 + 4);
    const unsigned o0 = f2bf(u.x * inv + bsc * bu.x) | ((unsigned)f2bf(u.y * inv + bsc * bu.y) << 16);
    const unsigned o1 = f2bf(u.z * inv + bsc * bu.z) | ((unsigned)f2bf(u.w * inv + bsc * bu.w) << 16);
    const unsigned o2 = f2bf(v.x * inv + bsc * bv.x) | ((unsigned)f2bf(v.y * inv + bsc * bv.y) << 16);
    const unsigned o3 = f2bf(v.z * inv + bsc * bv.z) | ((unsigned)f2bf(v.w * inv + bsc * bv.w) << 16);
    *(uint4*)&aggb[nl][c0] = make_uint4(o0, o1, o2, o3);
  }
  __syncthreads();

  // waves 0-1: gi = agg@Wih^T ; waves 2-3: gh = x@Whh^T
  const int isH = w >> 1;
  const int ctbase = (w & 1) * 12;
  const unsigned short* Wf = isH ? Whhf : Wihf;
  const float* bias = isH ? bhh : bih;
  const f32x4 zf = {0.0f, 0.0f, 0.0f, 0.0f};
  f32x4 acc[12];
#pragma unroll
  for (int i = 0; i < 12; ++i) acc[i] = zf;
#pragma unroll
  for (int ks = 0; ks < 4; ++ks) {
    bf16x8 bfrag;
    if (isH) {
      const float* xp = x + (size_t)(n0 + li) * 128 + ks * 32 + kg * 8;
      const float4 u = *(const float4*)xp, v = *(const float4*)(xp + 4);
      bfrag = pack8(u.x, u.y, u.z, u.w, v.x, v.y, v.z, v.w);
    } else {
      bfrag = *(const bf16x8*)&aggb[li][ks * 32 + kg * 8];
    }
#pragma unroll
    for (int i = 0; i < 12; ++i) {
      const int ct = ctbase + i;
      const bf16x8 af = *(const bf16x8*)(Wf + (size_t)(ct * 4 + ks) * 512 + lane * 8);
      acc[i] = __builtin_amdgcn_mfma_f32_16x16x32_bf16(af, bfrag, acc[i], 0, 0, 0);
    }
  }
#pragma unroll
  for (int i = 0; i < 12; ++i) {
    const int ocol = (ctbase + i) * 16 + kg * 4;
    const float4 bb = *(const float4*)(bias + ocol);
    const int col = isH * 384 + ocol;
    const unsigned lo = f2bf(acc[i][0] + bb.x) | ((unsigned)f2bf(acc[i][1] + bb.y) << 16);
    const unsigned hi = f2bf(acc[i][2] + bb.z) | ((unsigned)f2bf(acc[i][3] + bb.w) << 16);
    *(uint2*)&Ss[li][col] = make_uint2(lo, hi);
  }
  __syncthreads();

  // gates + residual + LN2
  const int nl = t >> 4, q0 = (t & 15) * 8;
  const int gn = n0 + nl;
  float xv[8];
  *(float4*)&xv[0] = *(const float4*)(x + (size_t)gn * 128 + q0);
  *(float4*)&xv[4] = *(const float4*)(x + (size_t)gn * 128 + q0 + 4);
  const uint4 gir = *(const uint4*)&Ss[nl][q0];
  const uint4 giz = *(const uint4*)&Ss[nl][q0 + 128];
  const uint4 gin = *(const uint4*)&Ss[nl][q0 + 256];
  const uint4 ghr = *(const uint4*)&Ss[nl][q0 + 384];
  const uint4 ghz = *(const uint4*)&Ss[nl][q0 + 512];
  const uint4 ghn = *(const uint4*)&Ss[nl][q0 + 640];
  const unsigned GIR[4] = {gir.x, gir.y, gir.z, gir.w};
  const unsigned GIZ[4] = {giz.x, giz.y, giz.z, giz.w};
  const unsigned GIN[4] = {gin.x, gin.y, gin.z, gin.w};
  const unsigned GHR[4] = {ghr.x, ghr.y, ghr.z, ghr.w};
  const unsigned GHZ[4] = {ghz.x, ghz.y, ghz.z, ghz.w};
  const unsigned GHN[4] = {ghn.x, ghn.y, ghn.z, ghn.w};
  float vb[8];
  float s1 = 0.0f, s2 = 0.0f;
#pragma unroll
  for (int j2 = 0; j2 < 4; ++j2) {
#pragma unroll
    for (int hl = 0; hl < 2; ++hl) {
      const int jj = j2 * 2 + hl;
      const unsigned sh = hl * 16;
      const float girv = bf2f((GIR[j2] >> sh) & 0xffffu);
      const float gizv = bf2f((GIZ[j2] >> sh) & 0xffffu);
      const float ginv = bf2f((GIN[j2] >> sh) & 0xffffu);
      const float ghrv = bf2f((GHR[j2] >> sh) & 0xffffu);
      const float ghzv = bf2f((GHZ[j2] >> sh) & 0xffffu);
      const float ghnv = bf2f((GHN[j2] >> sh) & 0xffffu);
      const float r = sigm(girv + ghrv);
      const float z = sigm(gizv + ghzv);
      const float nv = tanhf(ginv + r * ghnv);
      const float v = xv[jj] + (1.0f - z) * nv + z * xv[jj];
      vb[jj] = v; s1 += v; s2 += v * v;
    }
  }
  s1 += __shfl_xor(s1, 1); s2 += __shfl_xor(s2, 1);
  s1 += __shfl_xor(s1, 2); s2 += __shfl_xor(s2, 2);
  s1 += __shfl_xor(s1, 4); s2 += __shfl_xor(s2, 4);
  s1 += __shfl_xor(s1, 8); s2 += __shfl_xor(s2, 8);
  const float m = s1 * (1.0f / 128.0f);
  const float var = s2 * (1.0f / 128.0f) - m * m;
  const float rstd = rsqrtf(var + 1e-5f);
  float ov[8];
#pragma unroll
  for (int j = 0; j < 8; ++j)
    ov[j] = ln2g[q0 + j] * ((vb[j] - m) * rstd) + ln2b[q0 + j];
  *(float4*)(out + (size_t)gn * 128 + q0) = make_float4(ov[0], ov[1], ov[2], ov[3]);
  *(float4*)(out + (size_t)gn * 128 + q0 + 4) = make_float4(ov[4], ov[5], ov[6], ov[7]);
}

extern "C" void kernel_launch(void* const* d_in, const int* in_sizes, int n_in,
                              void* d_out, int out_size, void* d_ws, size_t ws_size,
                              hipStream_t stream) {
  const float* x         = (const float*)d_in[0];
  const float* edge_attr = (const float*)d_in[1];
  const float* pos       = (const float*)d_in[2];
  const float* W1        = (const float*)d_in[3];
  const float* b1        = (const float*)d_in[4];
  const float* ln1g      = (const float*)d_in[5];
  const float* ln1b      = (const float*)d_in[6];
  const float* W2        = (const float*)d_in[7];
  const float* b2        = (const float*)d_in[8];
  const float* Wih       = (const float*)d_in[9];
  const float* bih       = (const float*)d_in[10];
  const float* Whh       = (const float*)d_in[11];
  const float* bhh       = (const float*)d_in[12];
  const float* ln2g      = (const float*)d_in[13];
  const float* ln2b      = (const float*)d_in[14];
  const int*   ei        = (const int*)d_in[15];
  float* out = (float*)d_out;

  // ws layout (bytes)
  float*          sums  = (float*)d_ws;                                   // 25,600,000
  unsigned short* Pb    = (unsigned short*)((char*)d_ws + 25600000);      // 25,600,000
  unsigned short* frags = (unsigned short*)((char*)d_ws + 51200000);      //    303,104
  int*            deg   = (int*)((char*)d_ws + 51600000);                 //    200,000
  int*            cur   = (int*)((char*)d_ws + 51800000);                 //    200,000
  int*            offs  = (int*)((char*)d_ws + 52000000);                 //    200,000
  int*            bsum  = (int*)((char*)d_ws + 52200000);                 //        784
  int*            boff  = (int*)((char*)d_ws + 52204096);                 //        784
  int*            perm  = (int*)((char*)d_ws + 52300000);                 //  3,200,000
  unsigned short* W1ef = frags;               // 8 frags
  unsigned short* W2f  = frags + 8 * 512;     // 32 frags
  unsigned short* W1nf = frags + 40 * 512;    // 64 frags
  unsigned short* Wihf = frags + 104 * 512;   // 96 frags
  unsigned short* Whhf = frags + 200 * 512;   // 96 frags

  hipMemsetAsync(sums, 0, (size_t)NN * 128 * sizeof(float), stream);
  hipMemsetAsync(deg, 0, 2 * 200000, stream);   // deg + cur

  k0_prep<<<296, 64, 0, stream>>>(W1, W2, Wih, Whh, frags);
  k_hist<<<3125, 256, 0, stream>>>(ei, deg);
  kA_partial<<<196, 256, 0, stream>>>(deg, bsum);
  kB_scan<<<1, 256, 0, stream>>>(bsum, boff);
  kC_offs<<<196, 256, 0, stream>>>(deg, boff, offs);
  k_scatter<<<3125, 256, 0, stream>>>(ei, offs, cur, perm);
  k1_node_pre<<<3125, 256, 0, stream>>>(x, W1nf, Pb);
  k2_edge<<<12500, 256, 0, stream>>>(Pb, edge_attr, pos, ei, perm, W1ef, W2f,
                                     b1, ln1g, ln1b, sums);
  k3_gru<<<3125, 256, 0, stream>>>(x, sums, deg, Wihf, Whhf, bih, bhh, b2,
                                   ln2g, ln2b, out);
}